// Round 4
// baseline (2284.103 us; speedup 1.0000x reference)
//
#include <hip/hip_runtime.h>
#include <stdint.h>

#define N_NODES 4096
#define N_EDGES 32768

typedef float f32;

__device__ __forceinline__ float sigm(float x) { return 1.f / (1.f + __expf(-x)); }

// ---------------------------------------------------------------------------
__global__ void zero_agg_kernel(float* __restrict__ agg) {
  agg[blockIdx.x * 256 + threadIdx.x] = 0.f;
}

// ---------------------------------------------------------------------------
// proj_node: h = relu(node_feats @ W_p + b_p)  -> h (f32, in d_out)
// ---------------------------------------------------------------------------
__global__ void proj_node_f(const float* __restrict__ nf,
                            const float* __restrict__ Wp,
                            const float* __restrict__ bp,
                            float* __restrict__ h) {
  int idx = blockIdx.x * 256 + threadIdx.x;   // over 4096*64
  int n = idx >> 6, c = idx & 63;
  float acc = bp[c];
  for (int k = 0; k < 64; ++k)
    acc = fmaf(nf[n * 64 + k], Wp[k * 64 + c], acc);
  h[idx] = fmaxf(acc, 0.f);
}

// ---------------------------------------------------------------------------
// proj_edge: e = relu(edge_attr @ W_pe + b_pe)  -> e (f32, in d_out)
// ---------------------------------------------------------------------------
__global__ void proj_edge_f(const float* __restrict__ ea,
                            const float* __restrict__ Wpe,
                            const float* __restrict__ bpe,
                            float* __restrict__ e) {
  int idx = blockIdx.x * 256 + threadIdx.x;   // over 32768*128
  int ee = idx >> 7, c = idx & 127;
  float acc = bpe[c];
  for (int k = 0; k < 16; ++k)
    acc = fmaf(ea[ee * 16 + k], Wpe[k * 128 + c], acc);
  e[idx] = fmaxf(acc, 0.f);
}

// ---------------------------------------------------------------------------
// fused_msg: msg[e,f] = sum_d h[row[e],d] * relu(bnn[d*64+f] + sum_k e[e,k]*Wnn[k,d*64+f])
// scattered into agg[col[e],f] via atomicAdd. Never materializes We.
// Block: 64 edges x 64 f. 256 threads; thread (te,tf) owns a 4x4 (e,f) tile.
// se (64x128 e-rows) staged once in LDS (pad to 132 for banks+alignment);
// Wnn chunk (64 k x 64 f) staged per (d, k-half). fp32 outer-product FMA.
// ---------------------------------------------------------------------------
__launch_bounds__(256)
__global__ void fused_msg_f(const float* __restrict__ ebf,
                            const float* __restrict__ hid,
                            const float* __restrict__ Wnn,
                            const float* __restrict__ bnn,
                            const int* __restrict__ eidx,
                            float* __restrict__ agg) {
  __shared__ __align__(16) float se[64 * 132];   // 33,792 B
  __shared__ __align__(16) float Bs[64 * 64];    // 16,384 B
  const int t = threadIdx.x;
  const int te = t >> 4, tf = t & 15;            // e-tile, f-tile
  const int ebase = blockIdx.x * 64;

  // stage se: 64 edges x 128 k (float4)
  for (int i = 0; i < 8; ++i) {
    int g = i * 256 + t;                         // < 2048 quads
    int e = g >> 5, k4 = g & 31;
    *(float4*)&se[e * 132 + k4 * 4] =
        *(const float4*)&ebf[(size_t)(ebase + e) * 128 + k4 * 4];
  }

  int rows[4], cols[4];
#pragma unroll
  for (int i = 0; i < 4; ++i) {
    rows[i] = eidx[ebase + te * 4 + i];
    cols[i] = eidx[N_EDGES + ebase + te * 4 + i];
  }

  float msg[4][4];
#pragma unroll
  for (int i = 0; i < 4; ++i)
#pragma unroll
    for (int j = 0; j < 4; ++j) msg[i][j] = 0.f;

  for (int d = 0; d < 64; ++d) {
    float acc[4][4];
#pragma unroll
    for (int i = 0; i < 4; ++i)
#pragma unroll
      for (int j = 0; j < 4; ++j) acc[i][j] = 0.f;

    for (int kh = 0; kh < 2; ++kh) {
      __syncthreads();
      // stage Bs[kk][ff] = Wnn[(kh*64+kk), d*64+ff]  (64x64, float4)
#pragma unroll
      for (int i = 0; i < 4; ++i) {
        int g = i * 256 + t;                     // < 1024 quads
        int kk = g >> 4, f4 = g & 15;
        *(float4*)&Bs[kk * 64 + f4 * 4] =
            *(const float4*)&Wnn[(size_t)(kh * 64 + kk) * 4096 + d * 64 + f4 * 4];
      }
      __syncthreads();

#pragma unroll
      for (int kq = 0; kq < 16; ++kq) {
        float4 a0 = *(const float4*)&se[(te * 4 + 0) * 132 + kh * 64 + kq * 4];
        float4 a1 = *(const float4*)&se[(te * 4 + 1) * 132 + kh * 64 + kq * 4];
        float4 a2 = *(const float4*)&se[(te * 4 + 2) * 132 + kh * 64 + kq * 4];
        float4 a3 = *(const float4*)&se[(te * 4 + 3) * 132 + kh * 64 + kq * 4];
        float4 b0 = *(const float4*)&Bs[(kq * 4 + 0) * 64 + tf * 4];
        float4 b1 = *(const float4*)&Bs[(kq * 4 + 1) * 64 + tf * 4];
        float4 b2 = *(const float4*)&Bs[(kq * 4 + 2) * 64 + tf * 4];
        float4 b3 = *(const float4*)&Bs[(kq * 4 + 3) * 64 + tf * 4];
#define FMA_ROW(ei, av)                                            \
        acc[ei][0] = fmaf(av.x, b0.x, acc[ei][0]);                 \
        acc[ei][1] = fmaf(av.x, b0.y, acc[ei][1]);                 \
        acc[ei][2] = fmaf(av.x, b0.z, acc[ei][2]);                 \
        acc[ei][3] = fmaf(av.x, b0.w, acc[ei][3]);                 \
        acc[ei][0] = fmaf(av.y, b1.x, acc[ei][0]);                 \
        acc[ei][1] = fmaf(av.y, b1.y, acc[ei][1]);                 \
        acc[ei][2] = fmaf(av.y, b1.z, acc[ei][2]);                 \
        acc[ei][3] = fmaf(av.y, b1.w, acc[ei][3]);                 \
        acc[ei][0] = fmaf(av.z, b2.x, acc[ei][0]);                 \
        acc[ei][1] = fmaf(av.z, b2.y, acc[ei][1]);                 \
        acc[ei][2] = fmaf(av.z, b2.z, acc[ei][2]);                 \
        acc[ei][3] = fmaf(av.z, b2.w, acc[ei][3]);                 \
        acc[ei][0] = fmaf(av.w, b3.x, acc[ei][0]);                 \
        acc[ei][1] = fmaf(av.w, b3.y, acc[ei][1]);                 \
        acc[ei][2] = fmaf(av.w, b3.z, acc[ei][2]);                 \
        acc[ei][3] = fmaf(av.w, b3.w, acc[ei][3]);
        FMA_ROW(0, a0)
        FMA_ROW(1, a1)
        FMA_ROW(2, a2)
        FMA_ROW(3, a3)
#undef FMA_ROW
      }
    }

    // finalize chunk d: relu + weight by h[row,d], accumulate into msg
    float4 bn = *(const float4*)&bnn[d * 64 + tf * 4];
#pragma unroll
    for (int i = 0; i < 4; ++i) {
      float hv = hid[rows[i] * 64 + d];
      msg[i][0] = fmaf(hv, fmaxf(acc[i][0] + bn.x, 0.f), msg[i][0]);
      msg[i][1] = fmaf(hv, fmaxf(acc[i][1] + bn.y, 0.f), msg[i][1]);
      msg[i][2] = fmaf(hv, fmaxf(acc[i][2] + bn.z, 0.f), msg[i][2]);
      msg[i][3] = fmaf(hv, fmaxf(acc[i][3] + bn.w, 0.f), msg[i][3]);
    }
  }

#pragma unroll
  for (int i = 0; i < 4; ++i)
#pragma unroll
    for (int j = 0; j < 4; ++j)
      atomicAdd(&agg[(size_t)cols[i] * 64 + tf * 4 + j], msg[i][j]);
}

// ---------------------------------------------------------------------------
// node_update: m = relu(agg + h@W_root + b_conv); GRU(r,z,n); h updated
// in place (in d_out). Block = 16 nodes, 256 threads. f32 LDS only.
// ---------------------------------------------------------------------------
__global__ void node_update_f(const float* __restrict__ agg,
                              float* __restrict__ hid,
                              const float* __restrict__ Wroot,
                              const float* __restrict__ bconv,
                              const float* __restrict__ wih,
                              const float* __restrict__ whh,
                              const float* __restrict__ bih,
                              const float* __restrict__ bhh) {
  __shared__ __align__(16) float sh[16 * 64];
  __shared__ __align__(16) float sm[16 * 64];
  __shared__ __align__(16) float sg[16 * 384];
  const int t = threadIdx.x;
  const int nb = blockIdx.x * 16;

  for (int i = 0; i < 4; ++i) sh[i * 256 + t] = hid[nb * 64 + i * 256 + t];
  __syncthreads();

  for (int i = 0; i < 4; ++i) {
    int idx = i * 256 + t;
    int nl = idx >> 6, dc = idx & 63;
    float acc = bconv[dc] + agg[nb * 64 + idx];
    for (int k = 0; k < 64; ++k)
      acc = fmaf(sh[nl * 64 + k], Wroot[k * 64 + dc], acc);
    sm[idx] = fmaxf(acc, 0.f);
  }
  __syncthreads();

  for (int i = 0; i < 24; ++i) {
    int idx = i * 256 + t;               // < 6144
    int nl = idx / 384, j2 = idx % 384;
    float acc;
    if (j2 < 192) {
      acc = bih[j2];
      for (int k = 0; k < 64; ++k)
        acc = fmaf(sm[nl * 64 + k], wih[k * 192 + j2], acc);
    } else {
      int j = j2 - 192;
      acc = bhh[j];
      for (int k = 0; k < 64; ++k)
        acc = fmaf(sh[nl * 64 + k], whh[k * 192 + j], acc);
    }
    sg[idx] = acc;
  }
  __syncthreads();

  for (int i = 0; i < 4; ++i) {
    int idx = i * 256 + t;
    int nl = idx >> 6, dc = idx & 63;
    const float* g = &sg[nl * 384];
    float ir = g[dc], iz = g[64 + dc], in_ = g[128 + dc];
    float hr = g[192 + dc], hz = g[256 + dc], hn = g[320 + dc];
    float r = sigm(ir + hr), z = sigm(iz + hz);
    float nc = tanhf(in_ + r * hn);
    hid[nb * 64 + idx] = (1.f - z) * nc + z * sh[nl * 64 + dc];
  }
}

// ---------------------------------------------------------------------------
// edge_mlp: e' = relu(relu([h[row]|h[col]|e] @ W_eu1 + b1) @ W_eu2 + b2)
// 32 edges per block; in-place on e (own rows staged to LDS first).
// ---------------------------------------------------------------------------
__launch_bounds__(256)
__global__ void edge_mlp_f(const float* __restrict__ hid,
                           float* __restrict__ ebf,
                           const int* __restrict__ eidx,
                           const float* __restrict__ We1,
                           const float* __restrict__ be1,
                           const float* __restrict__ We2,
                           const float* __restrict__ be2) {
  __shared__ __align__(16) float cat[32 * 256];   // 32 KB
  __shared__ __align__(16) float t1s[32 * 128];   // 16 KB
  const int t = threadIdx.x;
  const int ebase = blockIdx.x * 32;

  for (int g = t; g < 8192; g += 256) {
    int e = g >> 8, c = g & 255;
    float v;
    if (c < 64)        v = hid[eidx[ebase + e] * 64 + c];
    else if (c < 128)  v = hid[eidx[N_EDGES + ebase + e] * 64 + (c - 64)];
    else               v = ebf[(size_t)(ebase + e) * 128 + (c - 128)];
    cat[e * 256 + c] = v;
  }
  __syncthreads();

  for (int i = 0; i < 16; ++i) {
    int idx = i * 256 + t;               // 4096 outputs (32e x 128c)
    int e = idx >> 7, c = idx & 127;
    float acc = be1[c];
    for (int k = 0; k < 256; ++k)
      acc = fmaf(cat[e * 256 + k], We1[k * 128 + c], acc);
    t1s[e * 128 + c] = fmaxf(acc, 0.f);
  }
  __syncthreads();

  for (int i = 0; i < 16; ++i) {
    int idx = i * 256 + t;
    int e = idx >> 7, c = idx & 127;
    float acc = be2[c];
    for (int k = 0; k < 128; ++k)
      acc = fmaf(t1s[e * 128 + k], We2[k * 128 + c], acc);
    ebf[(size_t)(ebase + e) * 128 + c] = fmaxf(acc, 0.f);
  }
}

// ---------------------------------------------------------------------------
extern "C" void kernel_launch(void* const* d_in, const int* in_sizes, int n_in,
                              void* d_out, int out_size, void* d_ws, size_t ws_size,
                              hipStream_t stream) {
  const float* nf    = (const float*)d_in[0];
  const float* ea    = (const float*)d_in[1];
  const int*   eidx  = (const int*)d_in[2];
  const float* Wp    = (const float*)d_in[3];
  const float* bp    = (const float*)d_in[4];
  const float* Wpe   = (const float*)d_in[5];
  const float* bpe   = (const float*)d_in[6];
  const float* Wnn   = (const float*)d_in[7];
  const float* bnn   = (const float*)d_in[8];
  const float* Wroot = (const float*)d_in[9];
  const float* bconv = (const float*)d_in[10];
  const float* wih   = (const float*)d_in[11];
  const float* whh   = (const float*)d_in[12];
  const float* bih   = (const float*)d_in[13];
  const float* bhh   = (const float*)d_in[14];
  const float* We1   = (const float*)d_in[15];
  const float* be1   = (const float*)d_in[16];
  const float* We2   = (const float*)d_in[17];
  const float* be2   = (const float*)d_in[18];

  // h and e live directly in d_out (f32, per reference output dtype); both are
  // fully rewritten every launch before any read.
  float* hid = (float*)d_out;                 // 4096*64
  float* ebf = (float*)d_out + 4096 * 64;     // 32768*128

  // workspace: agg only (1 MB)
  float* agg = (float*)d_ws;

  proj_node_f<<<1024, 256, 0, stream>>>(nf, Wp, bp, hid);
  proj_edge_f<<<16384, 256, 0, stream>>>(ea, Wpe, bpe, ebf);

  for (int s = 0; s < 3; ++s) {
    zero_agg_kernel<<<1024, 256, 0, stream>>>(agg);
    fused_msg_f<<<512, 256, 0, stream>>>(ebf, hid, Wnn, bnn, eidx, agg);
    node_update_f<<<256, 256, 0, stream>>>(agg, hid, Wroot, bconv,
                                           wih, whh, bih, bhh);
    edge_mlp_f<<<1024, 256, 0, stream>>>(hid, ebf, eidx, We1, be1, We2, be2);
  }
}

// Round 6
// 509.311 us; speedup vs baseline: 4.4847x; 4.4847x over previous
//
#include <hip/hip_runtime.h>
#include <stdint.h>

typedef __attribute__((ext_vector_type(8))) _Float16 f16x8;
typedef __attribute__((ext_vector_type(4))) float f32x4;

#define N_NODES 4096
#define N_EDGES 32768

__device__ __forceinline__ float sigm(float x) { return 1.f / (1.f + __expf(-x)); }

// pack 8 consecutive f32 -> f16x8 (RNE)
__device__ __forceinline__ f16x8 packh8(const float* p) {
  f16x8 r;
#pragma unroll
  for (int i = 0; i < 8; ++i) r[i] = (_Float16)p[i];
  return r;
}

// ---------------------------------------------------------------------------
__global__ void zero_agg_kernel(float* __restrict__ agg) {
  agg[blockIdx.x * 256 + threadIdx.x] = 0.f;
}

// ---------------------------------------------------------------------------
// prep: WnnT[n][k] fp16 from Wnn[k][n] f32 (4096x128 <- 128x4096), LDS-tiled.
// ---------------------------------------------------------------------------
__global__ void prep_wnnT(const float* __restrict__ Wnn,
                          _Float16* __restrict__ WnnT) {
  __shared__ float tile[128][33];
  const int t = threadIdx.x;
  const int nb = blockIdx.x * 32;
  for (int i = 0; i < 16; ++i) {
    int g = i * 256 + t;          // 4096 = 128k x 32n
    int k = g >> 5, j = g & 31;
    tile[k][j] = Wnn[(size_t)k * 4096 + nb + j];
  }
  __syncthreads();
  for (int i = 0; i < 16; ++i) {
    int g = i * 256 + t;
    int j = g >> 7, k = g & 127;
    WnnT[(size_t)(nb + j) * 128 + k] = (_Float16)tile[k][j];
  }
}

// We1T[n=128][k=256] from We1[256][128]; We2T[n=128][k=128] from We2[128][128]
__global__ void prep_small(const float* __restrict__ We1,
                           const float* __restrict__ We2,
                           _Float16* __restrict__ We1T,
                           _Float16* __restrict__ We2T) {
  int idx = blockIdx.x * 256 + threadIdx.x;   // < 49152
  if (idx < 32768) {
    int n = idx >> 8, k = idx & 255;
    We1T[idx] = (_Float16)We1[(size_t)k * 128 + n];
  } else {
    int j = idx - 32768;
    int n = j >> 7, k = j & 127;
    We2T[j] = (_Float16)We2[(size_t)k * 128 + n];
  }
}

// ---------------------------------------------------------------------------
// proj_node: h = relu(node_feats @ W_p + b_p) -> hid f32 (in d_out)
// ---------------------------------------------------------------------------
__global__ void proj_node_f(const float* __restrict__ nf,
                            const float* __restrict__ Wp,
                            const float* __restrict__ bp,
                            float* __restrict__ h) {
  int idx = blockIdx.x * 256 + threadIdx.x;
  int n = idx >> 6, c = idx & 63;
  float acc = bp[c];
  for (int k = 0; k < 64; ++k)
    acc = fmaf(nf[n * 64 + k], Wp[k * 64 + c], acc);
  h[idx] = fmaxf(acc, 0.f);
}

// ---------------------------------------------------------------------------
// proj_edge: e = relu(edge_attr @ W_pe + b_pe); Wpe cached in LDS; 32 e/block.
// ---------------------------------------------------------------------------
__launch_bounds__(256)
__global__ void proj_edge_f2(const float* __restrict__ ea,
                             const float* __restrict__ Wpe,
                             const float* __restrict__ bpe,
                             float* __restrict__ e) {
  __shared__ float sw[16 * 128];
  __shared__ float sb[128];
  __shared__ float sa[32][17];
  const int t = threadIdx.x;
  const int ebase = blockIdx.x * 32;
  for (int g = t; g < 2048; g += 256) sw[g] = Wpe[g];
  if (t < 128) sb[t] = bpe[t];
  for (int g = t; g < 512; g += 256) {
    int r = g >> 4, k = g & 15;
    sa[r][k] = ea[(size_t)(ebase + r) * 16 + k];
  }
  __syncthreads();
  int c = t & 127, eg = t >> 7;
  float wc[16];
#pragma unroll
  for (int k = 0; k < 16; ++k) wc[k] = sw[k * 128 + c];
  float bv = sb[c];
#pragma unroll
  for (int i = 0; i < 16; ++i) {
    int ee = eg * 16 + i;
    float acc = bv;
#pragma unroll
    for (int k = 0; k < 16; ++k) acc = fmaf(sa[ee][k], wc[k], acc);
    e[(size_t)(ebase + ee) * 128 + c] = fmaxf(acc, 0.f);
  }
}

// ---------------------------------------------------------------------------
// fused_msg (MFMA, fp16): msg[e,f] = sum_d h[row[e],d]*relu(bnn[d*64+f] + (e@Wnn)[e,d*64+f])
// 128 edges/block, 256 blocks. A (e rows, fp16) persistent in regs; B fragments
// loaded per-lane direct from global WnnT (disjoint rows per wave -> no dup),
// register double-buffered; h kept f32 (Hs[d][e] transposed in LDS, broadcast
// reads). NO barriers in the K-loop. Scatter via atomicAdd.
// ---------------------------------------------------------------------------
__launch_bounds__(256, 2)
__global__ void fused_msg_m(const float* __restrict__ ebf,
                            const float* __restrict__ hid,
                            const _Float16* __restrict__ WnnT,
                            const float* __restrict__ bnn,
                            const int* __restrict__ eidx,
                            float* __restrict__ agg) {
  __shared__ float Hs[64 * 132];   // Hs[d*132+e] = hid[row[e]][d]
  const int t = threadIdx.x;
  const int w = t >> 6, l = t & 63, l15 = l & 15, q = l >> 4;
  const int ebase = blockIdx.x * 128;

  // stage Hs (transposed): 128 e x 16 d4; 16-lane groups share e (broadcast read)
#pragma unroll
  for (int i = 0; i < 8; ++i) {
    int g = i * 256 + t;
    int e = g >> 4, d4 = g & 15;
    int r = eidx[ebase + e];
    float4 v = *(const float4*)&hid[(size_t)r * 64 + d4 * 4];
    Hs[(d4 * 4 + 0) * 132 + e] = v.x;
    Hs[(d4 * 4 + 1) * 132 + e] = v.y;
    Hs[(d4 * 4 + 2) * 132 + e] = v.z;
    Hs[(d4 * 4 + 3) * 132 + e] = v.w;
  }

  // persistent A fragments: 128 edges x 128 k, f32 -> fp16 in regs
  f16x8 af[8][4];
#pragma unroll
  for (int m = 0; m < 8; ++m)
#pragma unroll
    for (int kk = 0; kk < 4; ++kk)
      af[m][kk] = packh8(&ebf[(size_t)(ebase + m * 16 + l15) * 128 + kk * 32 + q * 8]);

  float msg[8][4];
#pragma unroll
  for (int m = 0; m < 8; ++m)
#pragma unroll
    for (int rr = 0; rr < 4; ++rr) msg[m][rr] = 0.f;

  __syncthreads();

  // B fragment base: this lane's row within each chunk = w*16+l15, k-offset q*8
  const _Float16* wb = WnnT + (size_t)(w * 16 + l15) * 128 + q * 8;
  f16x8 bb[4], nb[4];
#pragma unroll
  for (int kk = 0; kk < 4; ++kk) bb[kk] = *(const f16x8*)(wb + kk * 32);

  for (int d = 0; d < 64; ++d) {
    if (d < 63) {
      const _Float16* p = wb + (size_t)(d + 1) * 8192;   // next chunk (64 rows x 128)
#pragma unroll
      for (int kk = 0; kk < 4; ++kk) nb[kk] = *(const f16x8*)(p + kk * 32);
    }
    float bnv = bnn[d * 64 + w * 16 + l15];
#pragma unroll
    for (int m = 0; m < 8; ++m) {
      f32x4 C = {0.f, 0.f, 0.f, 0.f};
#pragma unroll
      for (int kk = 0; kk < 4; ++kk)
        C = __builtin_amdgcn_mfma_f32_16x16x32_f16(af[m][kk], bb[kk], C, 0, 0, 0);
      float4 hv = *(const float4*)&Hs[d * 132 + m * 16 + q * 4];
      msg[m][0] = fmaf(hv.x, fmaxf(C[0] + bnv, 0.f), msg[m][0]);
      msg[m][1] = fmaf(hv.y, fmaxf(C[1] + bnv, 0.f), msg[m][1]);
      msg[m][2] = fmaf(hv.z, fmaxf(C[2] + bnv, 0.f), msg[m][2]);
      msg[m][3] = fmaf(hv.w, fmaxf(C[3] + bnv, 0.f), msg[m][3]);
    }
#pragma unroll
    for (int kk = 0; kk < 4; ++kk) bb[kk] = nb[kk];
  }

  const int* colp = eidx + N_EDGES;
#pragma unroll
  for (int m = 0; m < 8; ++m)
#pragma unroll
    for (int rr = 0; rr < 4; ++rr) {
      int col = colp[ebase + m * 16 + q * 4 + rr];
      atomicAdd(&agg[(size_t)col * 64 + w * 16 + l15], msg[m][rr]);
    }
}

// ---------------------------------------------------------------------------
// node_update: m = relu(agg + h@W_root + b_conv); GRU; hid (f32, d_out) in place.
// ---------------------------------------------------------------------------
__global__ void node_update_f(const float* __restrict__ agg,
                              float* __restrict__ hid,
                              const float* __restrict__ Wroot,
                              const float* __restrict__ bconv,
                              const float* __restrict__ wih,
                              const float* __restrict__ whh,
                              const float* __restrict__ bih,
                              const float* __restrict__ bhh) {
  __shared__ __align__(16) float sh[16 * 64];
  __shared__ __align__(16) float sm[16 * 64];
  __shared__ __align__(16) float sg[16 * 384];
  const int t = threadIdx.x;
  const int nb = blockIdx.x * 16;

  for (int i = 0; i < 4; ++i) sh[i * 256 + t] = hid[nb * 64 + i * 256 + t];
  __syncthreads();

  for (int i = 0; i < 4; ++i) {
    int idx = i * 256 + t;
    int nl = idx >> 6, dc = idx & 63;
    float acc = bconv[dc] + agg[nb * 64 + idx];
    for (int k = 0; k < 64; ++k)
      acc = fmaf(sh[nl * 64 + k], Wroot[k * 64 + dc], acc);
    sm[idx] = fmaxf(acc, 0.f);
  }
  __syncthreads();

  for (int i = 0; i < 24; ++i) {
    int idx = i * 256 + t;
    int nl = idx / 384, j2 = idx % 384;
    float acc;
    if (j2 < 192) {
      acc = bih[j2];
      for (int k = 0; k < 64; ++k)
        acc = fmaf(sm[nl * 64 + k], wih[k * 192 + j2], acc);
    } else {
      int j = j2 - 192;
      acc = bhh[j];
      for (int k = 0; k < 64; ++k)
        acc = fmaf(sh[nl * 64 + k], whh[k * 192 + j], acc);
    }
    sg[idx] = acc;
  }
  __syncthreads();

  for (int i = 0; i < 4; ++i) {
    int idx = i * 256 + t;
    int nl = idx >> 6, dc = idx & 63;
    const float* g = &sg[nl * 384];
    float ir = g[dc], iz = g[64 + dc], in_ = g[128 + dc];
    float hr = g[192 + dc], hz = g[256 + dc], hn = g[320 + dc];
    float r = sigm(ir + hr), z = sigm(iz + hz);
    float nc = tanhf(in_ + r * hn);
    hid[nb * 64 + idx] = (1.f - z) * nc + z * sh[nl * 64 + dc];
  }
}

// ---------------------------------------------------------------------------
// edge_mlp (MFMA, fp16): e' = relu(relu([h[row]|h[col]|e] @ We1 + b1) @ We2 + b2)
// 64 edges/block. cat staged to LDS as fp16; B fragments direct from global
// (per-wave disjoint rows). Hidden tile Ts in LDS (fp16). f32 in/out, in place.
// ---------------------------------------------------------------------------
__launch_bounds__(256)
__global__ void edge_mlp_m(const float* __restrict__ hid,
                           float* __restrict__ ebf,
                           const int* __restrict__ eidx,
                           const _Float16* __restrict__ We1T,
                           const float* __restrict__ be1,
                           const _Float16* __restrict__ We2T,
                           const float* __restrict__ be2) {
  __shared__ _Float16 As[64 * 264];   // 33,792 B
  __shared__ _Float16 Ts[64 * 136];   // 17,408 B
  const int t = threadIdx.x;
  const int w = t >> 6, l = t & 63, l15 = l & 15, q = l >> 4;
  const int mbase = blockIdx.x * 64;

  for (int g = t; g < 2048; g += 256) {
    int r = g >> 5, kg = g & 31;
    int e = mbase + r;
    const float* src;
    if (kg < 8)       src = &hid[(size_t)eidx[e] * 64 + kg * 8];
    else if (kg < 16) src = &hid[(size_t)eidx[N_EDGES + e] * 64 + (kg - 8) * 8];
    else              src = &ebf[(size_t)e * 128 + (kg - 16) * 8];
    *(f16x8*)&As[r * 264 + kg * 8] = packh8(src);
  }
  __syncthreads();

  f32x4 zero4 = {0.f, 0.f, 0.f, 0.f};
  f32x4 acc[4][2];
#pragma unroll
  for (int m = 0; m < 4; ++m)
#pragma unroll
    for (int nn = 0; nn < 2; ++nn) acc[m][nn] = zero4;

#pragma unroll
  for (int kc = 0; kc < 4; ++kc)
#pragma unroll
    for (int kk = 0; kk < 2; ++kk) {
      int ko = kc * 64 + kk * 32 + q * 8;
      f16x8 b0 = *(const f16x8*)(We1T + (size_t)(w * 32 + l15) * 256 + ko);
      f16x8 b1 = *(const f16x8*)(We1T + (size_t)(w * 32 + 16 + l15) * 256 + ko);
#pragma unroll
      for (int m = 0; m < 4; ++m) {
        f16x8 a = *(const f16x8*)&As[(m * 16 + l15) * 264 + ko];
        acc[m][0] = __builtin_amdgcn_mfma_f32_16x16x32_f16(a, b0, acc[m][0], 0, 0, 0);
        acc[m][1] = __builtin_amdgcn_mfma_f32_16x16x32_f16(a, b1, acc[m][1], 0, 0, 0);
      }
    }

#pragma unroll
  for (int m = 0; m < 4; ++m)
#pragma unroll
    for (int nn = 0; nn < 2; ++nn) {
      int col = w * 32 + nn * 16 + l15;
      float bv = be1[col];
#pragma unroll
      for (int rr = 0; rr < 4; ++rr) {
        int row = m * 16 + q * 4 + rr;
        Ts[row * 136 + col] = (_Float16)fmaxf(acc[m][nn][rr] + bv, 0.f);
      }
    }
  __syncthreads();

  f32x4 acc2[4][2];
#pragma unroll
  for (int m = 0; m < 4; ++m)
#pragma unroll
    for (int nn = 0; nn < 2; ++nn) acc2[m][nn] = zero4;

#pragma unroll
  for (int kc = 0; kc < 2; ++kc)
#pragma unroll
    for (int kk = 0; kk < 2; ++kk) {
      int ko = kc * 64 + kk * 32 + q * 8;
      f16x8 b0 = *(const f16x8*)(We2T + (size_t)(w * 32 + l15) * 128 + ko);
      f16x8 b1 = *(const f16x8*)(We2T + (size_t)(w * 32 + 16 + l15) * 128 + ko);
#pragma unroll
      for (int m = 0; m < 4; ++m) {
        f16x8 a = *(const f16x8*)&Ts[(m * 16 + l15) * 136 + ko];
        acc2[m][0] = __builtin_amdgcn_mfma_f32_16x16x32_f16(a, b0, acc2[m][0], 0, 0, 0);
        acc2[m][1] = __builtin_amdgcn_mfma_f32_16x16x32_f16(a, b1, acc2[m][1], 0, 0, 0);
      }
    }

#pragma unroll
  for (int m = 0; m < 4; ++m)
#pragma unroll
    for (int nn = 0; nn < 2; ++nn) {
      int col = w * 32 + nn * 16 + l15;
      float bv = be2[col];
#pragma unroll
      for (int rr = 0; rr < 4; ++rr) {
        int row = mbase + m * 16 + q * 4 + rr;
        ebf[(size_t)row * 128 + col] = fmaxf(acc2[m][nn][rr] + bv, 0.f);
      }
    }
}

// ---------------------------------------------------------------------------
extern "C" void kernel_launch(void* const* d_in, const int* in_sizes, int n_in,
                              void* d_out, int out_size, void* d_ws, size_t ws_size,
                              hipStream_t stream) {
  const float* nf    = (const float*)d_in[0];
  const float* ea    = (const float*)d_in[1];
  const int*   eidx  = (const int*)d_in[2];
  const float* Wp    = (const float*)d_in[3];
  const float* bp    = (const float*)d_in[4];
  const float* Wpe   = (const float*)d_in[5];
  const float* bpe   = (const float*)d_in[6];
  const float* Wnn   = (const float*)d_in[7];
  const float* bnn   = (const float*)d_in[8];
  const float* Wroot = (const float*)d_in[9];
  const float* bconv = (const float*)d_in[10];
  const float* wih   = (const float*)d_in[11];
  const float* whh   = (const float*)d_in[12];
  const float* bih   = (const float*)d_in[13];
  const float* bhh   = (const float*)d_in[14];
  const float* We1   = (const float*)d_in[15];
  const float* be1   = (const float*)d_in[16];
  const float* We2   = (const float*)d_in[17];
  const float* be2   = (const float*)d_in[18];

  // h and e live in d_out (f32 masters), fully rewritten every launch.
  float* hid = (float*)d_out;                 // 4096*64
  float* ebf = (float*)d_out + 4096 * 64;     // 32768*128

  // workspace: 2,195,456 B
  char* ws = (char*)d_ws;
  _Float16* WnnT = (_Float16*)(ws + 0);          // 1,048,576
  _Float16* We1T = (_Float16*)(ws + 1048576);    //    65,536
  _Float16* We2T = (_Float16*)(ws + 1114112);    //    32,768
  float*    agg  = (float*)(ws + 1146880);       // 1,048,576

  prep_wnnT<<<128, 256, 0, stream>>>(Wnn, WnnT);
  prep_small<<<192, 256, 0, stream>>>(We1, We2, We1T, We2T);
  proj_node_f<<<1024, 256, 0, stream>>>(nf, Wp, bp, hid);
  proj_edge_f2<<<1024, 256, 0, stream>>>(ea, Wpe, bpe, ebf);

  for (int s = 0; s < 3; ++s) {
    zero_agg_kernel<<<1024, 256, 0, stream>>>(agg);
    fused_msg_m<<<256, 256, 0, stream>>>(ebf, hid, WnnT, bnn, eidx, agg);
    node_update_f<<<256, 256, 0, stream>>>(agg, hid, Wroot, bconv,
                                           wih, whh, bih, bhh);
    edge_mlp_m<<<512, 256, 0, stream>>>(hid, ebf, eidx, We1T, be1, We2T, be2);
  }
}